// Round 3
// baseline (93.949 us; speedup 1.0000x reference)
//
#include <hip/hip_runtime.h>
#include <math.h>

// 6-qubit batched statevector sim, MFMA formulation.
//   Stage 1 (ubuild_kernel): the 3 variational layers form ONE batch-shared
//     complex 64x64 matrix U (columns = circuit applied to basis states).
//     Built by 64 quads (R2-verified quad-split code), stored bf16 in d_ws
//     as planes U_r[n][k], U_i[n][k], row stride 72 (bank-conflict pad).
//   Stage 2 (qmain_kernel): per element: encoding (VALU, computed directly
//     in MFMA A-frag layout) -> phi = psi x U^T via 32 mfma_16x16x32_bf16
//     per 16-element tile -> measurements via per-wave LDS scratch.
// Amp index n: bit5=q0 ... bit0=q5 (reference C-order flatten).

struct cf { float r, i; };

__device__ __forceinline__ cf cmul(cf a, cf b) {
    return { fmaf(a.r, b.r, -a.i * b.i), fmaf(a.r, b.i, a.i * b.r) };
}
__device__ __forceinline__ cf cmac(cf acc, cf g, cf v) {
    acc.r = fmaf(g.r, v.r, fmaf(-g.i, v.i, acc.r));
    acc.i = fmaf(g.r, v.i, fmaf(g.i, v.r, acc.i));
    return acc;
}

typedef short short8 __attribute__((ext_vector_type(8)));
typedef float f32x4 __attribute__((ext_vector_type(4)));

constexpr int DPP_X1  = 0xB1; // quad_perm [1,0,3,2] : lane ^ 1
constexpr int DPP_X2  = 0x4E; // quad_perm [2,3,0,1] : lane ^ 2
constexpr int DPP_C01 = 0xB4; // quad_perm [0,1,3,2] : swap lanes 2,3

template<int CTRL>
__device__ __forceinline__ float dppf(float v) {
    return __int_as_float(__builtin_amdgcn_mov_dpp(__float_as_int(v), CTRL, 0xF, 0xF, true));
}
template<int CTRL>
__device__ __forceinline__ cf dppc(cf v) { return { dppf<CTRL>(v.r), dppf<CTRL>(v.i) }; }

// truncate-pack two f32 -> two bf16 in one v_perm_b32
__device__ __forceinline__ unsigned pkbf(float lo, float hi) {
    return __builtin_amdgcn_perm(__float_as_uint(hi), __float_as_uint(lo), 0x07060302u);
}

// ---- R2-verified quad-split gate helpers (used by ubuild) ----
template<int M>
__device__ __forceinline__ void apply1q(cf* st, cf g00, cf g01, cf g10, cf g11) {
#pragma unroll
    for (int i = 0; i < 16; ++i) {
        if (i & M) continue;
        cf a = st[i], b = st[i + M];
        cf na = cmul(g00, a); na = cmac(na, g01, b);
        cf nb = cmul(g10, a); nb = cmac(nb, g11, b);
        st[i] = na; st[i + M] = nb;
    }
}
template<int XCTRL>
__device__ __forceinline__ void apply1q_lane(cf* st, bool hi, cf g00, cf g01, cf g10, cf g11) {
    cf ga, gb;
    ga.r = hi ? g11.r : g00.r;  ga.i = hi ? g11.i : g00.i;
    gb.r = hi ? g10.r : g01.r;  gb.i = hi ? g10.i : g01.i;
#pragma unroll
    for (int i = 0; i < 16; ++i) {
        cf part = dppc<XCTRL>(st[i]);
        cf n = cmul(ga, st[i]);
        n = cmac(n, gb, part);
        st[i] = n;
    }
}
template<int MC, int MT>
__device__ __forceinline__ void cnot_local(cf* st) {
#pragma unroll
    for (int i = 0; i < 16; ++i) {
        if ((i & MC) && !(i & MT)) { cf t = st[i]; st[i] = st[i + MT]; st[i + MT] = t; }
    }
}

// =============================== stage 1 ===============================
__global__ void ubuild_kernel(const float* __restrict__ theta,
                              unsigned short* __restrict__ W) {
    __shared__ float gs[18 * 8];
    const int t = threadIdx.x;
    if (t < 18) {
        const float* th = theta + t * 3;   // t = l*6 + q
        float sx, cx, sy, cy, sz, cz;
        __sincosf(0.5f * th[0], &sx, &cx);
        __sincosf(0.5f * th[1], &sy, &cy);
        __sincosf(0.5f * th[2], &sz, &cz);
        cf m00 = {  cy * cx,  sy * sx };
        cf m01 = { -sy * cx, -cy * sx };
        cf m10 = {  sy * cx, -cy * sx };
        cf m11 = {  cy * cx, -sy * sx };
        cf e0 = { cz, -sz }, e1 = { cz, sz };
        cf g00 = cmul(e0, m00), g01 = cmul(e0, m01);
        cf g10 = cmul(e1, m10), g11 = cmul(e1, m11);
        float* o = gs + t * 8;
        o[0] = g00.r; o[1] = g00.i; o[2] = g01.r; o[3] = g01.i;
        o[4] = g10.r; o[5] = g10.i; o[6] = g11.r; o[7] = g11.i;
    }
    __syncthreads();

    const int k = t >> 2;                  // basis column 0..63
    const int p = t & 3;
    const bool l1 = (p & 2) != 0;          // qubit-0 bit
    const bool l0 = (p & 1) != 0;          // qubit-1 bit

    cf st[16];
#pragma unroll
    for (int i = 0; i < 16; ++i) st[i] = { 0.f, 0.f };
    if ((k >> 4) == p) st[k & 15] = { 1.f, 0.f };   // psi = e_k

#pragma unroll 1
    for (int l = 0; l < 3; ++l) {
#pragma unroll
        for (int i = 0; i < 16; ++i) st[i] = dppc<DPP_C01>(st[i]);   // CNOT(0,1)
#pragma unroll
        for (int i = 0; i < 8; ++i) {                                // CNOT(1,2)
            cf lo = st[i], hi = st[i + 8];
            st[i].r     = l0 ? hi.r : lo.r;  st[i].i     = l0 ? hi.i : lo.i;
            st[i + 8].r = l0 ? lo.r : hi.r;  st[i + 8].i = l0 ? lo.i : hi.i;
        }
        cnot_local<8, 4>(st);   // CNOT(2,3)
        cnot_local<4, 2>(st);   // CNOT(3,4)
        cnot_local<2, 1>(st);   // CNOT(4,5)
#pragma unroll
        for (int i = 1; i < 16; i += 2) st[i] = dppc<DPP_X2>(st[i]); // CNOT(5,0)

        const float* gg = gs + l * 48;
#define G4(kk) cf{gg[8*(kk)+0], gg[8*(kk)+1]}, cf{gg[8*(kk)+2], gg[8*(kk)+3]}, \
               cf{gg[8*(kk)+4], gg[8*(kk)+5]}, cf{gg[8*(kk)+6], gg[8*(kk)+7]}
        apply1q_lane<DPP_X2>(st, l1, G4(0));   // qubit 0
        apply1q_lane<DPP_X1>(st, l0, G4(1));   // qubit 1
        apply1q<8>(st, G4(2));                 // qubit 2
        apply1q<4>(st, G4(3));                 // qubit 3
        apply1q<2>(st, G4(4));                 // qubit 4
        apply1q<1>(st, G4(5));                 // qubit 5
#undef G4
    }

    // U[n][k] = (circuit e_k)[n]; store bf16 RNE, row stride 72
#pragma unroll
    for (int i = 0; i < 16; ++i) {
        const int n = (p << 4) | i;
        unsigned ur = __float_as_uint(st[i].r); ur = (ur + 0x7FFFu + ((ur >> 16) & 1u)) >> 16;
        unsigned ui = __float_as_uint(st[i].i); ui = (ui + 0x7FFFu + ((ui >> 16) & 1u)) >> 16;
        W[n * 72 + k]        = (unsigned short)ur;
        W[4608 + n * 72 + k] = (unsigned short)ui;
    }
}

// =============================== stage 2 ===============================
__global__ __launch_bounds__(256, 3) void qmain_kernel(
    const float* __restrict__ x, const unsigned short* __restrict__ W,
    float* __restrict__ out) {
    __shared__ unsigned short Wr[64 * 72];   // 9216 B
    __shared__ unsigned short Wi[64 * 72];   // 9216 B
    __shared__ float sc[4][16 * 132];        // per-wave scratch, 33792 B
    const int t = threadIdx.x;
    {
        const unsigned* src = (const unsigned*)W;
        unsigned* dr = (unsigned*)Wr; unsigned* di = (unsigned*)Wi;
#pragma unroll 1
        for (int i = t; i < 2304; i += 256) { dr[i] = src[i]; di[i] = src[2304 + i]; }
    }
    __syncthreads();

    const int wave = t >> 6, lane = t & 63;
    const int l = lane & 15, c2 = lane >> 4;
    float* scb = sc[wave];

#pragma unroll 1
    for (int tt = 0; tt < 2; ++tt) {
        const int tile = (blockIdx.x * 4 + wave) * 2 + tt;
        const int E = tile << 4;

        // ---- encoding for element e = E + l, directly in A-frag layout ----
        // A[m=lane&15][k=(lane>>4)*8+j]; k bits: b5=q0(frag), b4=q1(c2>>1),
        // b3=q2(c2&1), b2b1b0=(q3,q4,q5)=j
        const int e = E + l;
        const float4* xv = (const float4*)(x + (size_t)e * 24);
        cf v0[6], v1[6];
#pragma unroll
        for (int q = 0; q < 6; ++q) {
            float4 xq = xv[q];
            float m = (xq.x + xq.y + xq.z + xq.w) * 0.25f;
            m = fminf(fmaxf(m, -6.f), 6.f);
            float a = m * 0.52359877559829887308f;   // pi/6
            float s2, c2v, s4, c4;
            __sincosf(0.50f * a, &s2, &c2v);
            __sincosf(0.25f * a, &s4, &c4);
            v0[q] = { c4 * c2v, -s4 * c2v };
            v1[q] = { s4 * s2, -c4 * s2 };
        }
        cf t34[4];
        t34[0] = cmul(v0[3], v0[4]); t34[1] = cmul(v0[3], v1[4]);
        t34[2] = cmul(v1[3], v0[4]); t34[3] = cmul(v1[3], v1[4]);
        cf w8[8];
#pragma unroll
        for (int a2 = 0; a2 < 4; ++a2) {
            w8[2 * a2]     = cmul(t34[a2], v0[5]);
            w8[2 * a2 + 1] = cmul(t34[a2], v1[5]);
        }
        cf f1 = (c2 & 2) ? v1[1] : v0[1];
        cf f2 = (c2 & 1) ? v1[2] : v0[2];
        cf pc = cmul(f1, f2);
        cf p0 = cmul(v0[0], pc), p1 = cmul(v1[0], pc);
        float ar0f[8], ai0f[8], ar1f[8], ai1f[8];
#pragma unroll
        for (int j = 0; j < 8; ++j) {
            cf a0 = cmul(p0, w8[j]); cf a1 = cmul(p1, w8[j]);
            ar0f[j] = a0.r; ai0f[j] = a0.i; ar1f[j] = a1.r; ai1f[j] = a1.i;
        }
        union U8 { short8 v; unsigned u[4]; };
        U8 ar0, ai0, ar1, ai1;
#pragma unroll
        for (int d = 0; d < 4; ++d) {
            ar0.u[d] = pkbf(ar0f[2 * d], ar0f[2 * d + 1]);
            ai0.u[d] = pkbf(ai0f[2 * d], ai0f[2 * d + 1]);
            ar1.u[d] = pkbf(ar1f[2 * d], ar1f[2 * d + 1]);
            ai1.u[d] = pkbf(ai1f[2 * d], ai1f[2 * d + 1]);
        }

        // ---- phi = psi * U^T : 8 MFMA per n-tile, scatter C-layout to LDS ----
        // B-frag: B[k=(lane>>4)*8+j][n=lane&15] -> read W[(nt*16+l)][k] rows
        // C/D: col(n)=lane&15, row(m)=(lane>>4)*4+reg
#pragma unroll
        for (int nt = 0; nt < 4; ++nt) {
            const unsigned short* rbr = &Wr[(nt * 16 + l) * 72 + c2 * 8];
            const unsigned short* rbi = &Wi[(nt * 16 + l) * 72 + c2 * 8];
            short8 br0 = *(const short8*)rbr;
            short8 br1 = *(const short8*)(rbr + 32);
            short8 bi0 = *(const short8*)rbi;
            short8 bi1 = *(const short8*)(rbi + 32);
            f32x4 z = { 0.f, 0.f, 0.f, 0.f };
            f32x4 rp = __builtin_amdgcn_mfma_f32_16x16x32_bf16(ar0.v, br0, z, 0, 0, 0);
            rp = __builtin_amdgcn_mfma_f32_16x16x32_bf16(ar1.v, br1, rp, 0, 0, 0);
            f32x4 rm = __builtin_amdgcn_mfma_f32_16x16x32_bf16(ai0.v, bi0, z, 0, 0, 0);
            rm = __builtin_amdgcn_mfma_f32_16x16x32_bf16(ai1.v, bi1, rm, 0, 0, 0);
            f32x4 ci = __builtin_amdgcn_mfma_f32_16x16x32_bf16(ar0.v, bi0, z, 0, 0, 0);
            ci = __builtin_amdgcn_mfma_f32_16x16x32_bf16(ar1.v, bi1, ci, 0, 0, 0);
            ci = __builtin_amdgcn_mfma_f32_16x16x32_bf16(ai0.v, br0, ci, 0, 0, 0);
            ci = __builtin_amdgcn_mfma_f32_16x16x32_bf16(ai1.v, br1, ci, 0, 0, 0);
#pragma unroll
            for (int rg = 0; rg < 4; ++rg) {
                const int el = c2 * 4 + rg;
                const int n = nt * 16 + l;
                float2 val = make_float2(rp[rg] - rm[rg], ci[rg]);
                *(float2*)&scb[el * 132 + n * 2] = val;   // ds_write_b64
            }
        }

        // ---- measurements: 4 lanes per element, 16 amps each ----
        // lane q=lane&3 holds amps n = q*16 + jj  (q0=q>>1, q1=q&1,
        // jj bits: b3=q2, b2=q3, b1=q4, b0=q5)
        const int q = lane & 3, el2 = lane >> 2;
        const float* sr = &scb[el2 * 132 + q * 32];
        cf s[16];
#pragma unroll
        for (int j = 0; j < 8; ++j) {
            f32x4 ld = *(const f32x4*)&sr[j * 4];
            s[2 * j]     = { ld[0], ld[1] };
            s[2 * j + 1] = { ld[2], ld[3] };
        }
        float p_all = 0.f, p_b3 = 0.f, p_b1 = 0.f;
#pragma unroll
        for (int j = 0; j < 16; ++j) {
            float pp = fmaf(s[j].r, s[j].r, s[j].i * s[j].i);
            p_all += pp;
            if (j & 8) p_b3 += pp;
            if (j & 2) p_b1 += pp;
        }
        float z2p = p_all - 2.f * p_b3;
        float z4p = p_all - 2.f * p_b1;
        float z0p = (q & 2) ? -p_all : p_all;
        float x1p = 0.f, x3p = 0.f, x5p = 0.f;
#pragma unroll
        for (int j = 0; j < 16; ++j) {
            float prr = dppf<DPP_X1>(s[j].r);      // partner lane q^1 = n^16
            float pii = dppf<DPP_X1>(s[j].i);
            x1p = fmaf(s[j].r, prr, fmaf(s[j].i, pii, x1p));
            x3p = fmaf(s[j].r, s[j ^ 4].r, fmaf(s[j].i, s[j ^ 4].i, x3p));
            x5p = fmaf(s[j].r, s[j ^ 1].r, fmaf(s[j].i, s[j ^ 1].i, x5p));
        }
        // quad butterfly: all 4 lanes get full sums
        z0p += dppf<DPP_X1>(z0p);  z0p += dppf<DPP_X2>(z0p);
        z2p += dppf<DPP_X1>(z2p);  z2p += dppf<DPP_X2>(z2p);
        z4p += dppf<DPP_X1>(z4p);  z4p += dppf<DPP_X2>(z4p);
        x1p += dppf<DPP_X1>(x1p);  x1p += dppf<DPP_X2>(x1p);
        x3p += dppf<DPP_X1>(x3p);  x3p += dppf<DPP_X2>(x3p);
        x5p += dppf<DPP_X1>(x5p);  x5p += dppf<DPP_X2>(x5p);

        // out[e][0..7] = [z0,x1,z2,x3,z4,x5,z0,x1]; lane q writes q and q+4
        float oa = (q == 0) ? z0p : (q == 1) ? x1p : (q == 2) ? z2p : x3p;
        float ob = (q == 0) ? z4p : (q == 1) ? x5p : (q == 2) ? z0p : x1p;
        const size_t obase = (size_t)(E + el2) * 8;
        out[obase + q]     = oa;
        out[obase + 4 + q] = ob;
    }
}

extern "C" void kernel_launch(void* const* d_in, const int* in_sizes, int n_in,
                              void* d_out, int out_size, void* d_ws, size_t ws_size,
                              hipStream_t stream) {
    const float* x     = (const float*)d_in[0];   // [B, 24] f32
    const float* theta = (const float*)d_in[1];   // [3, 6, 3] f32
    float* out = (float*)d_out;                   // [B, 8] f32
    const int B = in_sizes[0] / 24;               // 131072
    unsigned short* W = (unsigned short*)d_ws;    // 2 x 64 x 72 bf16 planes
    ubuild_kernel<<<1, 256, 0, stream>>>(theta, W);
    const int tiles = B / 16;                     // 8192
    qmain_kernel<<<tiles / 8, 256, 0, stream>>>(x, W, out);  // 4 waves x 2 tiles
}

// Round 4
// 89.864 us; speedup vs baseline: 1.0455x; 1.0455x over previous
//
#include <hip/hip_runtime.h>
#include <math.h>

// 6-qubit statevector sim, single launch. Each batch element is split across
// a 4-lane quad: qubit0 -> lane bit1, qubit1 -> lane bit0, qubits 2..5 ->
// local bits 3..0 of a 16-amplitude register array (32 VGPRs/lane of state).
// Cross-lane ops via quad_perm DPP. Layer loop rolled: code fits I$ (the R1
// fully-unrolled 64-amp version was front-end bound at 129 us; this runs
// <42 us and is invisible next to the harness's 256 MiB re-poison fills).

struct cf { float r, i; };

__device__ __forceinline__ cf cmul(cf a, cf b) {
    return { fmaf(a.r, b.r, -a.i * b.i), fmaf(a.r, b.i, a.i * b.r) };
}
// acc + g*v
__device__ __forceinline__ cf cmac(cf acc, cf g, cf v) {
    acc.r = fmaf(g.r, v.r, fmaf(-g.i, v.i, acc.r));
    acc.i = fmaf(g.r, v.i, fmaf(g.i, v.r, acc.i));
    return acc;
}

// quad_perm DPP: result lane L reads source lane sel[L] within its quad.
constexpr int DPP_X1  = 0xB1; // [1,0,3,2] : xor lane bit0 (qubit1 partner)
constexpr int DPP_X2  = 0x4E; // [2,3,0,1] : xor lane bit1 (qubit0 partner)
constexpr int DPP_C01 = 0xB4; // [0,1,3,2] : swap lanes 2,3  (CNOT q0->q1)

template<int CTRL>
__device__ __forceinline__ float dppf(float v) {
    return __int_as_float(__builtin_amdgcn_mov_dpp(__float_as_int(v), CTRL, 0xF, 0xF, true));
}
template<int CTRL>
__device__ __forceinline__ cf dppc(cf v) { return { dppf<CTRL>(v.r), dppf<CTRL>(v.i) }; }

// 1q gate on a LOCAL qubit (mask M within the 16-amp array)
template<int M>
__device__ __forceinline__ void apply1q(cf* st, cf g00, cf g01, cf g10, cf g11) {
#pragma unroll
    for (int i = 0; i < 16; ++i) {
        if (i & M) continue;
        cf a = st[i], b = st[i + M];
        cf na = cmul(g00, a); na = cmac(na, g01, b);
        cf nb = cmul(g10, a); nb = cmac(nb, g11, b);
        st[i] = na; st[i + M] = nb;
    }
}

// 1q gate on a LANE qubit: partner amplitude via DPP, coeff row picked by `hi`.
template<int XCTRL>
__device__ __forceinline__ void apply1q_lane(cf* st, bool hi, cf g00, cf g01, cf g10, cf g11) {
    cf ga, gb;
    ga.r = hi ? g11.r : g00.r;  ga.i = hi ? g11.i : g00.i;
    gb.r = hi ? g10.r : g01.r;  gb.i = hi ? g10.i : g01.i;
#pragma unroll
    for (int i = 0; i < 16; ++i) {
        cf part = dppc<XCTRL>(st[i]);
        cf n = cmul(ga, st[i]);
        n = cmac(n, gb, part);
        st[i] = n;
    }
}

// CNOT with both control+target local: register swap
template<int MC, int MT>
__device__ __forceinline__ void cnot_local(cf* st) {
#pragma unroll
    for (int i = 0; i < 16; ++i) {
        if ((i & MC) && !(i & MT)) { cf t = st[i]; st[i] = st[i + MT]; st[i + MT] = t; }
    }
}

__global__ __launch_bounds__(256, 4) void qsim_kernel(
    const float* __restrict__ x, const float* __restrict__ theta,
    float* __restrict__ out) {
    // ---- per-block: 18 fused RZ*RY*RX gate matrices into LDS ----
    __shared__ float gs[18 * 8];
    const int t = threadIdx.x;
    if (t < 18) {
        const float* th = theta + t * 3;   // t = l*6 + q
        float sx, cx, sy, cy, sz, cz;
        __sincosf(0.5f * th[0], &sx, &cx);
        __sincosf(0.5f * th[1], &sy, &cy);
        __sincosf(0.5f * th[2], &sz, &cz);
        cf m00 = {  cy * cx,  sy * sx };
        cf m01 = { -sy * cx, -cy * sx };
        cf m10 = {  sy * cx, -cy * sx };
        cf m11 = {  cy * cx, -sy * sx };
        cf e0 = { cz, -sz }, e1 = { cz, sz };
        cf g00 = cmul(e0, m00), g01 = cmul(e0, m01);
        cf g10 = cmul(e1, m10), g11 = cmul(e1, m11);
        float* o = gs + t * 8;
        o[0] = g00.r; o[1] = g00.i; o[2] = g01.r; o[3] = g01.i;
        o[4] = g10.r; o[5] = g10.i; o[6] = g11.r; o[7] = g11.i;
    }
    __syncthreads();

    const int g = blockIdx.x * 256 + t;
    const int e = g >> 2;                  // batch element
    const int p = g & 3;                   // lane within quad
    const bool l1 = (p & 2) != 0;          // qubit-0 bit
    const bool l0 = (p & 1) != 0;          // qubit-1 bit

    // ---- encoding ----
    const float4* xv = reinterpret_cast<const float4*>(x + (size_t)e * 24);
    cf v0[6], v1[6];
#pragma unroll
    for (int q = 0; q < 6; ++q) {
        float4 xq = xv[q];
        float m = (xq.x + xq.y + xq.z + xq.w) * 0.25f;
        m = fminf(fmaxf(m, -6.0f), 6.0f);
        float a = m * 0.52359877559829887308f;   // pi/6
        float s2, c2, s4, c4;
        __sincosf(0.50f * a, &s2, &c2);
        __sincosf(0.25f * a, &s4, &c4);
        v0[q] = { c4 * c2, -s4 * c2 };   // (RZ(a/2) RX(a)) |0>, amp 0
        v1[q] = { s4 * s2, -c4 * s2 };   // amp 1
    }

    // qubit0/1 factor chosen by lane bits; qubits 2..5 tensor-expanded locally
    cf f0, f1;
    f0.r = l1 ? v1[0].r : v0[0].r;  f0.i = l1 ? v1[0].i : v0[0].i;
    f1.r = l0 ? v1[1].r : v0[1].r;  f1.i = l0 ? v1[1].i : v0[1].i;

    cf st[16];
    st[0] = cmul(f0, f1);
#pragma unroll
    for (int q = 2; q < 6; ++q) {
        const int m = 8 >> (q - 2);
#pragma unroll
        for (int i = 0; i < 16; i += 2 * m) {
            st[i + m] = cmul(st[i], v1[q]);   // high half first
            st[i]     = cmul(st[i], v0[q]);
        }
    }

    // ---- 3 layers (rolled: keep code well under the 32 KB I$) ----
#pragma unroll 1
    for (int l = 0; l < 3; ++l) {
        // CNOT(0,1): lanes 2<->3 exchange all amplitudes
#pragma unroll
        for (int i = 0; i < 16; ++i) st[i] = dppc<DPP_C01>(st[i]);
        // CNOT(1,2): lanes with l0==1 swap st[j] <-> st[j^8]
#pragma unroll
        for (int i = 0; i < 8; ++i) {
            cf lo = st[i], hi = st[i + 8];
            st[i].r     = l0 ? hi.r : lo.r;  st[i].i     = l0 ? hi.i : lo.i;
            st[i + 8].r = l0 ? lo.r : hi.r;  st[i + 8].i = l0 ? lo.i : hi.i;
        }
        cnot_local<8, 4>(st);   // CNOT(2,3)
        cnot_local<4, 2>(st);   // CNOT(3,4)
        cnot_local<2, 1>(st);   // CNOT(4,5)
        // CNOT(5,0): odd local j exchange across lane bit1
#pragma unroll
        for (int i = 1; i < 16; i += 2) st[i] = dppc<DPP_X2>(st[i]);

        const float* gg = gs + l * 48;
#define G4(k) cf{gg[8*(k)+0], gg[8*(k)+1]}, cf{gg[8*(k)+2], gg[8*(k)+3]}, \
              cf{gg[8*(k)+4], gg[8*(k)+5]}, cf{gg[8*(k)+6], gg[8*(k)+7]}
        apply1q_lane<DPP_X2>(st, l1, G4(0));   // qubit 0
        apply1q_lane<DPP_X1>(st, l0, G4(1));   // qubit 1
        apply1q<8>(st, G4(2));                 // qubit 2
        apply1q<4>(st, G4(3));                 // qubit 3
        apply1q<2>(st, G4(4));                 // qubit 4
        apply1q<1>(st, G4(5));                 // qubit 5
#undef G4
    }

    // ---- measurements ----
    float z0 = 0.f, z2 = 0.f, z4 = 0.f, x1s = 0.f, x3s = 0.f, x5s = 0.f;
#pragma unroll
    for (int i = 0; i < 16; ++i) {
        float pr = fmaf(st[i].r, st[i].r, st[i].i * st[i].i);
        z0 += pr;
        z2 = (i & 8) ? z2 - pr : z2 + pr;   // qubit2 = local bit3
        z4 = (i & 2) ? z4 - pr : z4 + pr;   // qubit4 = local bit1
        cf part = dppc<DPP_X1>(st[i]);      // qubit1 partner (cross-lane)
        x1s = fmaf(st[i].r, part.r, fmaf(st[i].i, part.i, x1s));
        if (!(i & 4)) x3s = fmaf(st[i].r, st[i + 4].r, fmaf(st[i].i, st[i + 4].i, x3s));
        if (!(i & 1)) x5s = fmaf(st[i].r, st[i + 1].r, fmaf(st[i].i, st[i + 1].i, x5s));
    }
    if (l1) z0 = -z0;                       // qubit0 sign = lane bit1
    x3s *= 2.f; x5s *= 2.f;                 // x1s already counts both directions

    // quad butterfly reduction: all 4 lanes end with the full sums
    z0  += dppf<DPP_X1>(z0);   z0  += dppf<DPP_X2>(z0);
    z2  += dppf<DPP_X1>(z2);   z2  += dppf<DPP_X2>(z2);
    z4  += dppf<DPP_X1>(z4);   z4  += dppf<DPP_X2>(z4);
    x1s += dppf<DPP_X1>(x1s);  x1s += dppf<DPP_X2>(x1s);
    x3s += dppf<DPP_X1>(x3s);  x3s += dppf<DPP_X2>(x3s);
    x5s += dppf<DPP_X1>(x5s);  x5s += dppf<DPP_X2>(x5s);

    // out[e*8 + 0..7] = [z0, x1, z2, x3, z4, x5, z0, x1]; lane p writes p, p+4
    float o0 = l1 ? (l0 ? x3s : z2) : (l0 ? x1s : z0);
    float o1 = l1 ? (l0 ? x1s : z0) : (l0 ? x5s : z4);
    out[(size_t)e * 8 + p] = o0;
    out[(size_t)e * 8 + 4 + p] = o1;
}

extern "C" void kernel_launch(void* const* d_in, const int* in_sizes, int n_in,
                              void* d_out, int out_size, void* d_ws, size_t ws_size,
                              hipStream_t stream) {
    const float* x     = (const float*)d_in[0];   // [B, 24] f32
    const float* theta = (const float*)d_in[1];   // [3, 6, 3] f32
    float* out = (float*)d_out;                   // [B, 8] f32
    const int B = in_sizes[0] / 24;               // 131072
    const int threads = B * 4;                    // 4 lanes per element
    qsim_kernel<<<dim3(threads / 256), dim3(256), 0, stream>>>(x, theta, out);
}